// Round 5
// baseline (421.410 us; speedup 1.0000x reference)
//
#include <hip/hip_runtime.h>
#include <hip/hip_bf16.h>

// Problem constants
#define BATCH 96
#define CH    96
#define SEQ   96
#define NHEAD 8
#define DK    96
#define DMODEL 768   // NHEAD*DK
#define GRP   8
#define EPSV  1e-5f

typedef __bf16 bf16x8 __attribute__((ext_vector_type(8)));
typedef float  f32x4  __attribute__((ext_vector_type(4)));
typedef unsigned short u16;

#define MFMA16(a, b, c) __builtin_amdgcn_mfma_f32_16x16x32_bf16((a), (b), (c), 0, 0, 0)

__device__ __forceinline__ u16 f2bf(float f) {
    union { float f; unsigned int u; } c; c.f = f;
    unsigned int u = c.u + 0x7fffu + ((c.u >> 16) & 1u);   // RNE
    return (u16)(u >> 16);
}

// ---------------------------------------------------------------------------
// 1) Prep: GroupNorm (blocks 0..767) + weight transpose/cast (blocks 768..3071)
// ---------------------------------------------------------------------------
__global__ __launch_bounds__(128) void prep_kernel(
        const float* __restrict__ x, const float* __restrict__ gamma,
        const float* __restrict__ beta,
        const float* __restrict__ Wq, const float* __restrict__ Wk,
        const float* __restrict__ Wv, const float* __restrict__ Wo,
        float* __restrict__ xn, u16* __restrict__ xn_bf,
        u16* __restrict__ WqT, u16* __restrict__ WkT,
        u16* __restrict__ WvT, u16* __restrict__ WoT) {
    if (blockIdx.x < 768) {
        int bg = blockIdx.x;
        int b = bg >> 3, g = bg & 7;
        const float* xp = x + b * 9216 + g * 1152;
        float vals[9];
        float s = 0.f, ss = 0.f;
        #pragma unroll
        for (int r = 0; r < 9; ++r) {
            float v = xp[threadIdx.x + 128 * r];
            vals[r] = v; s += v; ss += v * v;
        }
        #pragma unroll
        for (int off = 32; off > 0; off >>= 1) {
            s  += __shfl_down(s, off);
            ss += __shfl_down(ss, off);
        }
        __shared__ float red[4];
        if ((threadIdx.x & 63) == 0) {
            red[(threadIdx.x >> 6) * 2]     = s;
            red[(threadIdx.x >> 6) * 2 + 1] = ss;
        }
        __syncthreads();
        s = red[0] + red[2]; ss = red[1] + red[3];
        float mu   = s * (1.0f / 1152.0f);
        float var  = ss * (1.0f / 1152.0f) - mu * mu;
        float rsig = rsqrtf(var + EPSV);
        #pragma unroll
        for (int r = 0; r < 9; ++r) {
            int e = threadIdx.x + 128 * r;
            int c = g * 12 + e / 96;
            float v = (vals[r] - mu) * rsig * gamma[c] + beta[c];
            int idx = b * 9216 + g * 1152 + e;
            xn[idx]    = v;
            xn_bf[idx] = f2bf(v);
        }
    } else {
        int t = blockIdx.x - 768;                 // 0..2303
        int seg = t / 576;
        int idx = (t - seg * 576) * 128 + threadIdx.x;   // 0..73727 exactly
        const float* src = seg == 0 ? Wq : seg == 1 ? Wk : seg == 2 ? Wv : Wo;
        u16* dst = seg == 0 ? WqT : seg == 1 ? WkT : seg == 2 ? WvT : WoT;
        float v = src[idx];                       // coalesced read
        if (seg < 3) {
            int k2 = idx / 768, n = idx - k2 * 768;     // src (96,768)
            dst[n * 96 + k2] = f2bf(v);                 // WT (768,96)
        } else {
            int k2 = idx / 96, n = idx - k2 * 96;       // src (768,96)
            dst[n * 768 + k2] = f2bf(v);                // WoT (96,768)
        }
    }
}

// ---------------------------------------------------------------------------
// 2) QKV projection, barrier-free, no LDS.  grid (768, 3): x=(b,h), y=seg.
//    seg 0: Q = t@Wq+bq     -> qs [bh][s][d]
//    seg 1: K = t@Wk+bk     -> ks [bh][s][d]
//    seg 2: V^T = WvT@t^T+bv -> vts[bh][d][s]  (swapped operands, no scatter)
//    Each of 6 waves owns 16 output rows; biases folded into acc init.
// ---------------------------------------------------------------------------
__global__ __launch_bounds__(384) void qkv_kernel(
        const u16* __restrict__ xn_bf,
        const u16* __restrict__ WqT, const u16* __restrict__ WkT,
        const u16* __restrict__ WvT,
        const float* __restrict__ bq, const float* __restrict__ bk,
        const float* __restrict__ bv,
        u16* __restrict__ qs, u16* __restrict__ ks, u16* __restrict__ vts) {
    int bh = blockIdx.x, seg = blockIdx.y;
    int b = bh >> 3, h = bh & 7;
    int wave = threadIdx.x >> 6, lane = threadIdx.x & 63;
    int ln = lane & 15, quad = lane >> 4;
    int m0 = wave * 16, hq = h * 96;
    const u16* xb = xn_bf + b * 9216;

    const u16* abase;
    const u16* bbase;
    u16* dst;
    if (seg == 0)      { abase = xb + (m0 + ln) * 96;        bbase = WqT + hq * 96; dst = qs; }
    else if (seg == 1) { abase = xb + (m0 + ln) * 96;        bbase = WkT + hq * 96; dst = ks; }
    else               { abase = WvT + (hq + m0 + ln) * 96;  bbase = xb;            dst = vts; }

    bf16x8 a[3];
    #pragma unroll
    for (int kt = 0; kt < 3; ++kt)
        a[kt] = *(const bf16x8*)(abase + kt * 32 + quad * 8);

    f32x4 acc[6];
    if (seg == 2) {
        float b0 = bv[hq + m0 + quad * 4];
        float b1 = bv[hq + m0 + quad * 4 + 1];
        float b2 = bv[hq + m0 + quad * 4 + 2];
        float b3 = bv[hq + m0 + quad * 4 + 3];
        #pragma unroll
        for (int nt = 0; nt < 6; ++nt) acc[nt] = f32x4{b0, b1, b2, b3};
    } else {
        const float* bias = (seg == 0) ? bq : bk;
        #pragma unroll
        for (int nt = 0; nt < 6; ++nt) {
            float c = bias[hq + nt * 16 + ln];
            acc[nt] = f32x4{c, c, c, c};
        }
    }

    #pragma unroll
    for (int kt = 0; kt < 3; ++kt)
        #pragma unroll
        for (int nt = 0; nt < 6; ++nt) {
            bf16x8 bb = *(const bf16x8*)(bbase + (nt * 16 + ln) * 96 + kt * 32 + quad * 8);
            acc[nt] = MFMA16(a[kt], bb, acc[nt]);
        }

    u16* o = dst + (size_t)bh * 9216;
    #pragma unroll
    for (int nt = 0; nt < 6; ++nt)
        #pragma unroll
        for (int r = 0; r < 4; ++r)
            o[(m0 + quad * 4 + r) * 96 + nt * 16 + ln] = f2bf(acc[nt][r]);
}

// ---------------------------------------------------------------------------
// 3) Attention, fully wave-independent (zero __syncthreads).
//    grid 1152 x 256 threads = 4608 waves; wave w -> (bh = w/6, tile = w%6).
//    QK^T from global q/k (L1/L2-resident per bh), causal softmax in
//    registers, P via private per-wave LDS patch (intra-wave DS ordering),
//    PV from global vt.
// ---------------------------------------------------------------------------
__global__ __launch_bounds__(256) void attn_kernel(
        const u16* __restrict__ qs, const u16* __restrict__ ks,
        const u16* __restrict__ vts, u16* __restrict__ ab) {
    __shared__ __align__(16) u16 pb[4][16][104];   // per-wave P patch
    int wave = threadIdx.x >> 6, lane = threadIdx.x & 63;
    int ln = lane & 15, quad = lane >> 4;
    unsigned w = blockIdx.x * 4 + wave;            // 0..4607
    unsigned bh = w / 6;
    int m0 = (int)(w - bh * 6) * 16;
    int b = bh >> 3, h = bh & 7;
    const u16* q  = qs  + (size_t)bh * 9216;
    const u16* k  = ks  + (size_t)bh * 9216;
    const u16* vt = vts + (size_t)bh * 9216;

    // ---- scores = QK^T ----
    bf16x8 aa[3];
    #pragma unroll
    for (int kt = 0; kt < 3; ++kt)
        aa[kt] = *(const bf16x8*)(q + (m0 + ln) * 96 + kt * 32 + quad * 8);
    f32x4 accs[6] = {};
    #pragma unroll
    for (int kt = 0; kt < 3; ++kt)
        #pragma unroll
        for (int nt = 0; nt < 6; ++nt) {
            bf16x8 bb = *(const bf16x8*)(k + (nt * 16 + ln) * 96 + kt * 32 + quad * 8);
            accs[nt] = MFMA16(aa[kt], bb, accs[nt]);
        }

    // ---- causal softmax in registers; C layout row=quad*4+r, col=nt*16+ln
    const float scale = 0.10206207261596577f;   // 1/sqrt(96)
    float pout[4][6];
    #pragma unroll
    for (int r = 0; r < 4; ++r) {
        int row = m0 + quad * 4 + r;
        float vals[6], m = -1e30f;
        #pragma unroll
        for (int nt = 0; nt < 6; ++nt) {
            int col = nt * 16 + ln;
            float sv = accs[nt][r] * scale;
            vals[nt] = (col <= row) ? sv : -1e30f;
            m = fmaxf(m, vals[nt]);
        }
        #pragma unroll
        for (int off = 1; off < 16; off <<= 1) m = fmaxf(m, __shfl_xor(m, off));
        float sum = 0.f;
        #pragma unroll
        for (int nt = 0; nt < 6; ++nt) {
            float p = (vals[nt] > -1e29f) ? __expf(vals[nt] - m) : 0.f;
            pout[r][nt] = p; sum += p;
        }
        #pragma unroll
        for (int off = 1; off < 16; off <<= 1) sum += __shfl_xor(sum, off);
        float rinv = 1.0f / sum;
        #pragma unroll
        for (int nt = 0; nt < 6; ++nt) pout[r][nt] *= rinv;
    }

    // ---- P -> private LDS patch (intra-wave RAW; DS ops in-order per wave)
    #pragma unroll
    for (int r = 0; r < 4; ++r)
        #pragma unroll
        for (int nt = 0; nt < 6; ++nt)
            pb[wave][quad * 4 + r][nt * 16 + ln] = f2bf(pout[r][nt]);

    // ---- O = P @ V  (A = own P rows, B = vt rows from global) ----
    f32x4 acco[6] = {};
    #pragma unroll
    for (int kt = 0; kt < 3; ++kt) {
        bf16x8 pa = *(const bf16x8*)(&pb[wave][ln][kt * 32 + quad * 8]);
        #pragma unroll
        for (int nt = 0; nt < 6; ++nt) {
            bf16x8 bb = *(const bf16x8*)(vt + (nt * 16 + ln) * 96 + kt * 32 + quad * 8);
            acco[nt] = MFMA16(pa, bb, acco[nt]);
        }
    }
    const size_t obase = (size_t)b * 96 * DMODEL + h * 96;
    #pragma unroll
    for (int nt = 0; nt < 6; ++nt) {
        int d = nt * 16 + ln;
        #pragma unroll
        for (int r = 0; r < 4; ++r) {
            int row = m0 + quad * 4 + r;
            ab[obase + (size_t)row * DMODEL + d] = f2bf(acco[nt][r]);
        }
    }
}

// ---------------------------------------------------------------------------
// 4) Fused out-projection + broadcast residual, i-split 4 ways.
//    grid 2304 = (j, k0q, iq), block 384 (6 waves).  Proj tile recomputed
//    per i-quarter (WoT L2-resident); Phase D streams 24x16x96 output slab
//    with nontemporal stores and division-free addressing.
// ---------------------------------------------------------------------------
__global__ __launch_bounds__(384) void obcast_kernel(
        const u16* __restrict__ attn, const u16* __restrict__ WoT,
        const float* __restrict__ bo, const float* __restrict__ xn,
        float* __restrict__ out) {
    __shared__ __align__(16) float red[6][16][96];   // 36864 B
    __shared__ __align__(16) float xnt[24][96];      //  9216 B
    int wave = threadIdx.x >> 6, lane = threadIdx.x & 63;
    int ln = lane & 15, quad = lane >> 4;

    int bid = blockIdx.x;
    int iq = bid & 3;                       // i quarter
    int jk = bid >> 2;                      // 0..575
    int j  = jk / 6;                        // attention batch
    int k0 = (jk - j * 6) * 16;             // seq offset within batch j
    int m0 = jk * 16;                       // proj rows [m0, m0+16)
    int i0 = iq * 24;

    // Phase A: xn[i0..i0+24)[j][:] -> LDS (576 f32x4; 384 + 192 threads)
    {
        const f32x4* xn4 = (const f32x4*)xn;
        f32x4* xt4 = (f32x4*)xnt;
        int idx = threadIdx.x;                     // 0..383
        int i = idx / 24, l4 = idx - i * 24;
        xt4[idx] = xn4[(size_t)((i0 + i) * 96 + j) * 24 + l4];
        if (threadIdx.x < 192) {
            int idx2 = threadIdx.x + 384;
            int i2 = idx2 / 24, l42 = idx2 - i2 * 24;
            xt4[idx2] = xn4[(size_t)((i0 + i2) * 96 + j) * 24 + l42];
        }
    }

    // Phase B: attn(16x768) @ Wo(768x96), K split 6 ways (128 per wave)
    int kw = wave * 128;
    f32x4 acc[6] = {};
    #pragma unroll
    for (int kt = 0; kt < 4; ++kt) {
        bf16x8 a = *(const bf16x8*)(attn + (size_t)(m0 + ln) * DMODEL + kw + kt * 32 + quad * 8);
        #pragma unroll
        for (int nt = 0; nt < 6; ++nt) {
            bf16x8 bb = *(const bf16x8*)(WoT + (nt * 16 + ln) * DMODEL + kw + kt * 32 + quad * 8);
            acc[nt] = MFMA16(a, bb, acc[nt]);
        }
    }
    #pragma unroll
    for (int nt = 0; nt < 6; ++nt)
        #pragma unroll
        for (int r = 0; r < 4; ++r)
            red[wave][quad * 4 + r][nt * 16 + ln] = acc[nt][r];
    __syncthreads();

    // Phase C: K-reduce + bias, in place into red[0] (owner-computes)
    #pragma unroll
    for (int e = 0; e < 4; ++e) {
        int idx = threadIdx.x + e * 384;           // 0..1535
        int row = idx / 96, col = idx - row * 96;
        red[0][row][col] = red[0][row][col] + red[1][row][col] +
                           red[2][row][col] + red[3][row][col] +
                           red[4][row][col] + red[5][row][col] + bo[col];
    }
    __syncthreads();

    // Phase D: stream the 24x16x96 output slab; no divisions in the loop
    f32x4* out4 = (f32x4*)out;
    const f32x4* pt4 = (const f32x4*)red;          // red[0]: 16 x 24 f32x4
    const f32x4* xt4 = (const f32x4*)xnt;          // 24 x 24 f32x4
    int k  = threadIdx.x / 24;                     // 384 = 16*24 exactly
    int l4 = threadIdx.x - k * 24;
    f32x4 pv = pt4[k * 24 + l4];
    size_t o = ((size_t)(i0 * 96 + j) * 96 + (k0 + k)) * 24 + l4;
    #pragma unroll
    for (int i = 0; i < 24; ++i) {
        f32x4 rr = pv + xt4[i * 24 + l4];
        __builtin_nontemporal_store(rr, &out4[o]);
        o += 221184;                               // 96*96*96/4 per i step
    }
}

// ---------------------------------------------------------------------------
extern "C" void kernel_launch(void* const* d_in, const int* in_sizes, int n_in,
                              void* d_out, int out_size, void* d_ws, size_t ws_size,
                              hipStream_t stream) {
    const float* x     = (const float*)d_in[0];
    const float* Wq    = (const float*)d_in[1];
    const float* bq    = (const float*)d_in[2];
    const float* Wk    = (const float*)d_in[3];
    const float* bk    = (const float*)d_in[4];
    const float* Wv    = (const float*)d_in[5];
    const float* bv    = (const float*)d_in[6];
    const float* Wo    = (const float*)d_in[7];
    const float* bo    = (const float*)d_in[8];
    const float* gamma = (const float*)d_in[9];
    const float* beta  = (const float*)d_in[10];
    float* out = (float*)d_out;

    // workspace layout (bytes), peak ~62.5 MB
    char* ws = (char*)d_ws;
    float* xn_f = (float*)(ws + 0);                 //  3,538,944
    u16*  xn_b  = (u16*)(ws + 3538944);             //  1,769,472
    u16*  WqT   = (u16*)(ws + 5308416);             //    147,456
    u16*  WkT   = (u16*)(ws + 5455872);
    u16*  WvT   = (u16*)(ws + 5603328);
    u16*  WoT   = (u16*)(ws + 5750784);
    u16*  qsb   = (u16*)(ws + 5898240);             // 14,155,776
    u16*  ksb   = (u16*)(ws + 20054016);            // 14,155,776
    u16*  vtsb  = (u16*)(ws + 34209792);            // 14,155,776
    u16*  ab    = (u16*)(ws + 48365568);            // 14,155,776 -> 62,521,344

    prep_kernel<<<dim3(3072), dim3(128), 0, stream>>>(
        x, gamma, beta, Wq, Wk, Wv, Wo, xn_f, xn_b, WqT, WkT, WvT, WoT);
    qkv_kernel<<<dim3(768, 3), dim3(384), 0, stream>>>(
        xn_b, WqT, WkT, WvT, bq, bk, bv, qsb, ksb, vtsb);
    attn_kernel<<<dim3(1152), dim3(256), 0, stream>>>(qsb, ksb, vtsb, ab);
    obcast_kernel<<<dim3(2304), dim3(384), 0, stream>>>(ab, WoT, bo, xn_f, out);
}

// Round 7
// 408.881 us; speedup vs baseline: 1.0306x; 1.0306x over previous
//
#include <hip/hip_runtime.h>
#include <hip/hip_bf16.h>

// Problem constants
#define BATCH 96
#define CH    96
#define SEQ   96
#define NHEAD 8
#define DK    96
#define DMODEL 768   // NHEAD*DK
#define GRP   8
#define EPSV  1e-5f

typedef __bf16 bf16x8 __attribute__((ext_vector_type(8)));
typedef float  f32x4  __attribute__((ext_vector_type(4)));
typedef unsigned short u16;

#define MFMA16(a, b, c) __builtin_amdgcn_mfma_f32_16x16x32_bf16((a), (b), (c), 0, 0, 0)

__device__ __forceinline__ u16 f2bf(float f) {
    union { float f; unsigned int u; } c; c.f = f;
    unsigned int u = c.u + 0x7fffu + ((c.u >> 16) & 1u);   // RNE
    return (u16)(u >> 16);
}

// ---------------------------------------------------------------------------
// 1) Prep: GroupNorm (blocks 0..767) + weight transpose/cast (blocks 768..3071)
//    gn: one block per (b,g), 128 threads x 9 elems (1152 per group).
//    wconv: source-linear iteration -> coalesced 4B reads; scattered 2B
//    stores are fire-and-forget.
// ---------------------------------------------------------------------------
__global__ __launch_bounds__(128) void prep_kernel(
        const float* __restrict__ x, const float* __restrict__ gamma,
        const float* __restrict__ beta,
        const float* __restrict__ Wq, const float* __restrict__ Wk,
        const float* __restrict__ Wv, const float* __restrict__ Wo,
        float* __restrict__ xn, u16* __restrict__ xn_bf,
        u16* __restrict__ WqT, u16* __restrict__ WkT,
        u16* __restrict__ WvT, u16* __restrict__ WoT) {
    if (blockIdx.x < 768) {
        int bg = blockIdx.x;
        int b = bg >> 3, g = bg & 7;
        const float* xp = x + b * 9216 + g * 1152;
        float vals[9];
        float s = 0.f, ss = 0.f;
        #pragma unroll
        for (int r = 0; r < 9; ++r) {
            float v = xp[threadIdx.x + 128 * r];
            vals[r] = v; s += v; ss += v * v;
        }
        #pragma unroll
        for (int off = 32; off > 0; off >>= 1) {
            s  += __shfl_down(s, off);
            ss += __shfl_down(ss, off);
        }
        __shared__ float red[4];
        if ((threadIdx.x & 63) == 0) {
            red[(threadIdx.x >> 6) * 2]     = s;
            red[(threadIdx.x >> 6) * 2 + 1] = ss;
        }
        __syncthreads();
        s = red[0] + red[2]; ss = red[1] + red[3];
        float mu   = s * (1.0f / 1152.0f);
        float var  = ss * (1.0f / 1152.0f) - mu * mu;
        float rsig = rsqrtf(var + EPSV);
        #pragma unroll
        for (int r = 0; r < 9; ++r) {
            int e = threadIdx.x + 128 * r;
            int c = g * 12 + e / 96;
            float v = (vals[r] - mu) * rsig * gamma[c] + beta[c];
            int idx = b * 9216 + g * 1152 + e;
            xn[idx]    = v;
            xn_bf[idx] = f2bf(v);
        }
    } else {
        int t = blockIdx.x - 768;                 // 0..2303
        int seg = t / 576;
        int idx = (t - seg * 576) * 128 + threadIdx.x;   // 0..73727 exactly
        const float* src = seg == 0 ? Wq : seg == 1 ? Wk : seg == 2 ? Wv : Wo;
        u16* dst = seg == 0 ? WqT : seg == 1 ? WkT : seg == 2 ? WvT : WoT;
        float v = src[idx];                       // coalesced read
        if (seg < 3) {
            int k2 = idx / 768, n = idx - k2 * 768;     // src (96,768)
            dst[n * 96 + k2] = f2bf(v);                 // WT (768,96)
        } else {
            int k2 = idx / 96, n = idx - k2 * 96;       // src (768,96)
            dst[n * 768 + k2] = f2bf(v);                // WoT (96,768)
        }
    }
}

// ---------------------------------------------------------------------------
// 2) Fused QKV + attention per (b,h).  grid 768, block 384 (6 waves).
//    Single __syncthreads() total: P gets its own LDS buffer (pb), so the
//    P write->read is intra-wave only (DS ops are in-order within a wave);
//    the old 2 barriers around the kb-reuse are gone.  QKV as three
//    sequential sub-GEMMs (L1-resident weight slices); biases folded into
//    accumulator init.  LDS 78 KB -> still 2 blocks/CU.
// ---------------------------------------------------------------------------
__global__ __launch_bounds__(384) void fattn_kernel(
        const u16* __restrict__ xn_bf,
        const u16* __restrict__ WqT, const u16* __restrict__ WkT,
        const u16* __restrict__ WvT,
        const float* __restrict__ bq, const float* __restrict__ bk,
        const float* __restrict__ bv,
        u16* __restrict__ attn_out) {
    int b = blockIdx.x >> 3, h = blockIdx.x & 7;
    __shared__ __align__(16) u16 qb[96][104];
    __shared__ __align__(16) u16 kb[96][104];
    __shared__ __align__(16) u16 vt[96][104];   // vt[d][s]
    __shared__ __align__(16) u16 pb[96][104];   // P, private rows per wave

    int wave = threadIdx.x >> 6, lane = threadIdx.x & 63;
    int ln = lane & 15, quad = lane >> 4;
    int m0 = wave * 16;
    const u16* xb = xn_bf + b * 9216;
    const int hq = h * 96;

    // ---- A-operands (rows of t for q/k; rows of Wv^T for v^T) ----
    bf16x8 a[3], av[3];
    #pragma unroll
    for (int kt = 0; kt < 3; ++kt) {
        a[kt]  = *(const bf16x8*)(xb + (m0 + ln) * 96 + kt * 32 + quad * 8);
        av[kt] = *(const bf16x8*)(WvT + (hq + m0 + ln) * 96 + kt * 32 + quad * 8);
    }

    // ---- accumulators initialized with biases ----
    float bvr[4];
    #pragma unroll
    for (int r = 0; r < 4; ++r) bvr[r] = bv[hq + m0 + quad * 4 + r];
    f32x4 aq[6], ak[6], avv[6];
    #pragma unroll
    for (int nt = 0; nt < 6; ++nt) {
        float bqc = bq[hq + nt * 16 + ln];
        float bkc = bk[hq + nt * 16 + ln];
        aq[nt]  = f32x4{bqc, bqc, bqc, bqc};
        ak[nt]  = f32x4{bkc, bkc, bkc, bkc};
        avv[nt] = f32x4{bvr[0], bvr[1], bvr[2], bvr[3]};
    }

    // ---- Q sub-GEMM (working set: WqT slice 18KB + xb 18KB) ----
    #pragma unroll
    for (int kt = 0; kt < 3; ++kt)
        #pragma unroll
        for (int nt = 0; nt < 6; ++nt) {
            bf16x8 bqf = *(const bf16x8*)(WqT + (hq + nt * 16 + ln) * 96 + kt * 32 + quad * 8);
            aq[nt] = MFMA16(a[kt], bqf, aq[nt]);
        }
    // ---- K sub-GEMM ----
    #pragma unroll
    for (int kt = 0; kt < 3; ++kt)
        #pragma unroll
        for (int nt = 0; nt < 6; ++nt) {
            bf16x8 bkf = *(const bf16x8*)(WkT + (hq + nt * 16 + ln) * 96 + kt * 32 + quad * 8);
            ak[nt] = MFMA16(a[kt], bkf, ak[nt]);
        }
    // ---- V^T sub-GEMM (B = rows of t) ----
    #pragma unroll
    for (int kt = 0; kt < 3; ++kt)
        #pragma unroll
        for (int nt = 0; nt < 6; ++nt) {
            bf16x8 bvf = *(const bf16x8*)(xb + (nt * 16 + ln) * 96 + kt * 32 + quad * 8);
            avv[nt] = MFMA16(av[kt], bvf, avv[nt]);
        }

    #pragma unroll
    for (int nt = 0; nt < 6; ++nt) {
        int col = nt * 16 + ln;
        #pragma unroll
        for (int r = 0; r < 4; ++r) {
            int row = m0 + quad * 4 + r;
            qb[row][col] = f2bf(aq[nt][r]);
            kb[row][col] = f2bf(ak[nt][r]);
            vt[row][col] = f2bf(avv[nt][r]);   // row=d, col=s
        }
    }
    __syncthreads();   // the ONLY barrier: kb/vt visible to all waves

    // ---- scores = QK^T (A = own q rows, B = all k rows) ----
    f32x4 accs[6] = {};
    #pragma unroll
    for (int kt = 0; kt < 3; ++kt) {
        bf16x8 aa = *(const bf16x8*)(&qb[m0 + ln][kt * 32 + quad * 8]);
        #pragma unroll
        for (int nt = 0; nt < 6; ++nt) {
            bf16x8 bb = *(const bf16x8*)(&kb[nt * 16 + ln][kt * 32 + quad * 8]);
            accs[nt] = MFMA16(aa, bb, accs[nt]);
        }
    }

    // ---- causal softmax in registers; C layout row=quad*4+r, col=nt*16+ln
    const float scale = 0.10206207261596577f;   // 1/sqrt(96)
    float pout[4][6];
    #pragma unroll
    for (int r = 0; r < 4; ++r) {
        int row = m0 + quad * 4 + r;
        float vals[6], m = -1e30f;
        #pragma unroll
        for (int nt = 0; nt < 6; ++nt) {
            int col = nt * 16 + ln;
            float sv = accs[nt][r] * scale;
            vals[nt] = (col <= row) ? sv : -1e30f;
            m = fmaxf(m, vals[nt]);
        }
        #pragma unroll
        for (int off = 1; off < 16; off <<= 1) m = fmaxf(m, __shfl_xor(m, off));
        float sum = 0.f;
        #pragma unroll
        for (int nt = 0; nt < 6; ++nt) {
            float p = (vals[nt] > -1e29f) ? __expf(vals[nt] - m) : 0.f;
            pout[r][nt] = p; sum += p;
        }
        #pragma unroll
        for (int off = 1; off < 16; off <<= 1) sum += __shfl_xor(sum, off);
        float rinv = 1.0f / sum;
        #pragma unroll
        for (int nt = 0; nt < 6; ++nt) pout[r][nt] *= rinv;
    }

    // ---- P -> private pb rows (intra-wave RAW only; no barrier needed) ----
    #pragma unroll
    for (int r = 0; r < 4; ++r)
        #pragma unroll
        for (int nt = 0; nt < 6; ++nt)
            pb[m0 + quad * 4 + r][nt * 16 + ln] = f2bf(pout[r][nt]);

    // ---- O = P @ V  (A = own P rows, B = all vt rows) ----
    f32x4 acco[6] = {};
    #pragma unroll
    for (int kt = 0; kt < 3; ++kt) {
        bf16x8 aa = *(const bf16x8*)(&pb[m0 + ln][kt * 32 + quad * 8]);
        #pragma unroll
        for (int nt = 0; nt < 6; ++nt) {
            bf16x8 bb = *(const bf16x8*)(&vt[nt * 16 + ln][kt * 32 + quad * 8]);
            acco[nt] = MFMA16(aa, bb, acco[nt]);
        }
    }
    const size_t obase = (size_t)b * 96 * DMODEL + hq;
    #pragma unroll
    for (int nt = 0; nt < 6; ++nt) {
        int d = nt * 16 + ln;
        #pragma unroll
        for (int r = 0; r < 4; ++r) {
            int row = m0 + quad * 4 + r;
            attn_out[obase + (size_t)row * DMODEL + d] = f2bf(acco[nt][r]);
        }
    }
}

// ---------------------------------------------------------------------------
// 3) Fused out-projection + broadcast residual, i-split 4 ways.
//    grid 2304 = (j, k0q, iq), block 384 (6 waves).  Proj tile recomputed
//    per i-quarter (WoT L2-resident); Phase D streams 24x16x96 output slab
//    with nontemporal stores and division-free addressing.
// ---------------------------------------------------------------------------
__global__ __launch_bounds__(384) void obcast_kernel(
        const u16* __restrict__ attn, const u16* __restrict__ WoT,
        const float* __restrict__ bo, const float* __restrict__ xn,
        float* __restrict__ out) {
    __shared__ __align__(16) float red[6][16][96];   // 36864 B
    __shared__ __align__(16) float xnt[24][96];      //  9216 B
    int wave = threadIdx.x >> 6, lane = threadIdx.x & 63;
    int ln = lane & 15, quad = lane >> 4;

    int bid = blockIdx.x;
    int iq = bid & 3;                       // i quarter
    int jk = bid >> 2;                      // 0..575
    int j  = jk / 6;                        // attention batch
    int k0 = (jk - j * 6) * 16;             // seq offset within batch j
    int m0 = jk * 16;                       // proj rows [m0, m0+16)
    int i0 = iq * 24;

    // Phase A: xn[i0..i0+24)[j][:] -> LDS (576 f32x4; 384 + 192 threads)
    {
        const f32x4* xn4 = (const f32x4*)xn;
        f32x4* xt4 = (f32x4*)xnt;
        int idx = threadIdx.x;                     // 0..383
        int i = idx / 24, l4 = idx - i * 24;
        xt4[idx] = xn4[(size_t)((i0 + i) * 96 + j) * 24 + l4];
        if (threadIdx.x < 192) {
            int idx2 = threadIdx.x + 384;
            int i2 = idx2 / 24, l42 = idx2 - i2 * 24;
            xt4[idx2] = xn4[(size_t)((i0 + i2) * 96 + j) * 24 + l42];
        }
    }

    // Phase B: attn(16x768) @ Wo(768x96), K split 6 ways (128 per wave)
    int kw = wave * 128;
    f32x4 acc[6] = {};
    #pragma unroll
    for (int kt = 0; kt < 4; ++kt) {
        bf16x8 a = *(const bf16x8*)(attn + (size_t)(m0 + ln) * DMODEL + kw + kt * 32 + quad * 8);
        #pragma unroll
        for (int nt = 0; nt < 6; ++nt) {
            bf16x8 bb = *(const bf16x8*)(WoT + (nt * 16 + ln) * DMODEL + kw + kt * 32 + quad * 8);
            acc[nt] = MFMA16(a, bb, acc[nt]);
        }
    }
    #pragma unroll
    for (int nt = 0; nt < 6; ++nt)
        #pragma unroll
        for (int r = 0; r < 4; ++r)
            red[wave][quad * 4 + r][nt * 16 + ln] = acc[nt][r];
    __syncthreads();

    // Phase C: K-reduce + bias, in place into red[0] (owner-computes)
    #pragma unroll
    for (int e = 0; e < 4; ++e) {
        int idx = threadIdx.x + e * 384;           // 0..1535
        int row = idx / 96, col = idx - row * 96;
        red[0][row][col] = red[0][row][col] + red[1][row][col] +
                           red[2][row][col] + red[3][row][col] +
                           red[4][row][col] + red[5][row][col] + bo[col];
    }
    __syncthreads();

    // Phase D: stream the 24x16x96 output slab; no divisions in the loop
    f32x4* out4 = (f32x4*)out;
    const f32x4* pt4 = (const f32x4*)red;          // red[0]: 16 x 24 f32x4
    const f32x4* xt4 = (const f32x4*)xnt;          // 24 x 24 f32x4
    int k  = threadIdx.x / 24;                     // 384 = 16*24 exactly
    int l4 = threadIdx.x - k * 24;
    f32x4 pv = pt4[k * 24 + l4];
    size_t o = ((size_t)(i0 * 96 + j) * 96 + (k0 + k)) * 24 + l4;
    #pragma unroll
    for (int i = 0; i < 24; ++i) {
        f32x4 rr = pv + xt4[i * 24 + l4];
        __builtin_nontemporal_store(rr, &out4[o]);
        o += 221184;                               // 96*96*96/4 per i step
    }
}

// ---------------------------------------------------------------------------
extern "C" void kernel_launch(void* const* d_in, const int* in_sizes, int n_in,
                              void* d_out, int out_size, void* d_ws, size_t ws_size,
                              hipStream_t stream) {
    const float* x     = (const float*)d_in[0];
    const float* Wq    = (const float*)d_in[1];
    const float* bq    = (const float*)d_in[2];
    const float* Wk    = (const float*)d_in[3];
    const float* bk    = (const float*)d_in[4];
    const float* Wv    = (const float*)d_in[5];
    const float* bv    = (const float*)d_in[6];
    const float* Wo    = (const float*)d_in[7];
    const float* bo    = (const float*)d_in[8];
    const float* gamma = (const float*)d_in[9];
    const float* beta  = (const float*)d_in[10];
    float* out = (float*)d_out;

    // workspace layout (bytes), ~23.6 MB
    char* ws = (char*)d_ws;
    float* xn_f = (float*)(ws + 0);                 //  3,538,944
    u16*  xn_b  = (u16*)(ws + 3538944);             //  1,769,472
    u16*  WqT   = (u16*)(ws + 5308416);             //    147,456
    u16*  WkT   = (u16*)(ws + 5455872);
    u16*  WvT   = (u16*)(ws + 5603328);
    u16*  WoT   = (u16*)(ws + 5750784);
    u16*  ab    = (u16*)(ws + 5898240);             // 14,155,776

    prep_kernel<<<dim3(3072), dim3(128), 0, stream>>>(
        x, gamma, beta, Wq, Wk, Wv, Wo, xn_f, xn_b, WqT, WkT, WvT, WoT);
    fattn_kernel<<<dim3(BATCH * NHEAD), dim3(384), 0, stream>>>(
        xn_b, WqT, WkT, WvT, bq, bk, bv, ab);
    obcast_kernel<<<dim3(2304), dim3(384), 0, stream>>>(ab, WoT, bo, xn_f, out);
}